// Round 5
// baseline (181.779 us; speedup 1.0000x reference)
//
#include <hip/hip_runtime.h>
#include <hip/hip_bf16.h>
#include <stdint.h>

#define Bb 16
#define Nn 1024
#define Hh 8
#define Dd 64

typedef unsigned short u16;
typedef float f32x4 __attribute__((ext_vector_type(4)));
typedef short short8 __attribute__((ext_vector_type(8)));

union U4S8 { uint4 u; short8 s; };
union BF2U { __hip_bfloat162 h; uint32_t u; };

__device__ __forceinline__ uint32_t f2bf(float f){
  union{float f;uint32_t i;} v; v.f=f;
  return (v.i + 0x7fffu + ((v.i>>16)&1u))>>16;
}

__device__ __forceinline__ f32x4 mfma16(short8 a, short8 b, f32x4 c){
  return __builtin_amdgcn_mfma_f32_16x16x32_bf16(a,b,c,0,0,0);
}

// log2(10000)/32
#define ROPE_K 0.41524101186092030f
// 0.125 * log2(e)  (sm_scale folded with exp->exp2 conversion)
#define QS 0.18033688011112042f
#define NEGBIG -1.0e30f

// ============================================================
// cos/sin table, layout [n][i]: tab[(n<<5)+i] = {cos(n*invfreq_i),
// sin(n*invfreq_i)}, n in [0,1024), i in [0,32).  256 KB, 32K sincos.
// ============================================================
__global__ __launch_bounds__(256) void rope_table_kernel(float2* __restrict__ tab)
{
  int id = blockIdx.x*256 + threadIdx.x;   // 32768 total
  int n = id >> 5, i = id & 31;
  float inv = exp2f(-(float)i * ROPE_K);
  float sn, cs; sincosf((float)n * inv, &sn, &cs);
  tab[id] = make_float2(cs, sn);
}

// ============================================================
// Fused staging: per tile, 512 threads each load 8 K f32 + 8 V f32 +
// 4 cos/sin pairs (all 32B contiguous), rope K / permute V in regs,
// write fragment-linear LDS.  Loads issue at top of iter kt (T14
// split); writes land after PV, so HBM latency hides under compute.
// Fragment-linear layouts (per tile of 4096 u16), verified in R0-R4:
//   K elem = kb*1024 + half*512 + quad*128 + l15*8 + j
//   V elem = s*1024  + half*512 + qd*128  + l15v*8 + j,
//     slot(k) = (k&1) | ((k>>4)&3)<<1 | ((k>>2)&3)<<3 | ((k>>1)&1)<<5
// ============================================================
struct Stage {
  float4 ka0, ka1, va0, va1, c0, c1;
};

__device__ __forceinline__ void stage_load(Stage& S,
    const float* __restrict__ xk, const float* __restrict__ xv,
    const float2* __restrict__ tab, int b, int h, int n, int sd0)
{
  const float4* kg = (const float4*)(xk + ((((size_t)b*Nn + n)*Hh + h)<<6) + sd0);
  S.ka0 = kg[0]; S.ka1 = kg[1];
  const float4* vg = (const float4*)(xv + ((((size_t)b*Nn + n)*Hh + h)<<6) + sd0);
  S.va0 = vg[0]; S.va1 = vg[1];
  const float4* tg = (const float4*)(tab + (n<<5) + (sd0>>1));  // 32B aligned
  S.c0 = tg[0]; S.c1 = tg[1];
}

__device__ __forceinline__ void stage_write(const Stage& S,
    u16* __restrict__ Kl, u16* __restrict__ Vl,
    int kdest, int sd0, int vhalf, int vqd, int vj)
{
  float kx[8]  = {S.ka0.x,S.ka0.y,S.ka0.z,S.ka0.w, S.ka1.x,S.ka1.y,S.ka1.z,S.ka1.w};
  float cs4[4] = {S.c0.x, S.c0.z, S.c1.x, S.c1.z};
  float sn4[4] = {S.c0.y, S.c0.w, S.c1.y, S.c1.w};
  uint32_t w[4];
  #pragma unroll
  for (int j=0;j<4;++j){
    float x0 = kx[2*j], x1 = kx[2*j+1];
    float q0 = x0*cs4[j] - x1*sn4[j];
    float q1 = x1*cs4[j] + x0*sn4[j];
    w[j] = f2bf(q0) | (f2bf(q1)<<16);
  }
  *(uint4*)&Kl[kdest] = make_uint4(w[0],w[1],w[2],w[3]);
  float vvv[8] = {S.va0.x,S.va0.y,S.va0.z,S.va0.w, S.va1.x,S.va1.y,S.va1.z,S.va1.w};
  #pragma unroll
  for (int jj=0;jj<8;++jj){
    int d = sd0 + jj;
    Vl[((d>>4)<<10) + (vhalf<<9) + (vqd<<7) + ((d&15)<<3) + vj] = (u16)f2bf(vvv[jj]);
  }
}

// ============================================================
// Fused attention.  R4 showed attn8=56us but total=176us: the ~120us
// non-attn residual is the prepass pipeline (its dispatch + the 67MB
// Kf/Vf HBM round-trip + launches) -- structural, so it's removed.
// Grid 512 x 512thr (8 waves), 2 blocks/CU all-resident, 256 q rows
// per block (per-wave compute identical to verified R4: mb=2).  Each
// block ropes K / permutes V from raw f32 into LDS itself; 4 blocks
// per (b,h) share an XCD so redundant f32 reads are L2 hits.
// ============================================================
__global__ __launch_bounds__(512,4) void fused_attn_kernel(
    const float* __restrict__ xq, const float* __restrict__ xk,
    const float* __restrict__ xv, const int* __restrict__ vis,
    const float2* __restrict__ tab, float* __restrict__ out)
{
  __shared__ u16 KV[2][2][4096];    // [buf][K/V][frag-linear], 32 KiB
  __shared__ float biasS[Nn];       // key-bias 0 / -1e30, 4 KiB

  const int tid  = threadIdx.x;     // 0..511
  const int lane = tid & 63;
  const int wave = tid >> 6;        // 0..7
  const int l15  = lane & 15;
  const int quad = lane >> 4;

  // ---- XCD-aware decode (grid 512, 8 XCDs, 64 blocks/XCD) ----
  const int bid = blockIdx.x;
  const int xcd = bid & 7;
  const int ix  = bid >> 3;            // 0..63
  const int bh_ = (xcd<<4) | (ix>>2);  // 16 bh per XCD, 4 qt adjacent
  const int qt  = ix & 3;
  const int h   = bh_ & 7;
  const int b   = bh_ >> 3;
  const int qbase = qt<<8;             // 256 q rows per block

  const int* visb = vis + b*Nn;

  // ---- staging thread mapping (per tile: 64 rows x 64 d) ----
  const int srow = tid >> 3;           // key row in tile
  const int sd0  = (tid & 7) << 3;     // 8-d block
  const int kdest = ((srow>>4)<<10) + ((sd0>>5)<<9) + (((sd0>>3)&3)<<7) + ((srow&15)<<3);
  const int slot = (srow&1) | (((srow>>4)&3)<<1) | (((srow>>2)&3)<<3) | (((srow>>1)&1)<<5);
  const int vhalf = slot>>5, vqd = (slot>>3)&3, vj = slot&7;

  // ---- stage vis -> f32 bias in LDS (once) ----
  {
    int2 vi = *(const int2*)&visb[tid<<1];
    float2 bs;
    bs.x = vi.x ? 0.f : NEGBIG;
    bs.y = vi.y ? 0.f : NEGBIG;
    *(float2*)&biasS[tid<<1] = bs;
  }

  // ---- roped Q B-frags in registers (QS folded), 2 m-blocks ----
  short8 qa[2][2];
  #pragma unroll
  for (int mb=0; mb<2; ++mb){
    int n = qbase + (wave<<5) + (mb<<4) + l15;
    const float* src = xq + ((((size_t)b*Nn + n)*Hh + h)<<6);
    #pragma unroll
    for (int half=0; half<2; ++half){
      int d0 = (half<<5) + (quad<<3);
      const float4* g = (const float4*)(src + d0);
      float4 u0 = g[0], u1 = g[1];
      float xx[8] = {u0.x,u0.y,u0.z,u0.w, u1.x,u1.y,u1.z,u1.w};
      uint32_t w[4];
      #pragma unroll
      for (int j=0;j<4;++j){
        int i2 = (d0>>1) + j;
        float2 t = tab[(n<<5)+i2];
        float x0 = xx[2*j], x1 = xx[2*j+1];
        float q0 = (x0*t.x - x1*t.y)*QS;
        float q1 = (x1*t.x + x0*t.y)*QS;
        w[j] = f2bf(q0) | (f2bf(q1)<<16);
      }
      U4S8 t2; t2.u = make_uint4(w[0],w[1],w[2],w[3]);
      qa[mb][half] = t2.s;
    }
  }

  U4S8 ones_u; ones_u.u = make_uint4(0x3F803F80u,0x3F803F80u,0x3F803F80u,0x3F803F80u);
  const short8 ones = ones_u.s;

  f32x4 acc[2][4];
  f32x4 l_acc[2];
  #pragma unroll
  for (int mb=0;mb<2;++mb){
    l_acc[mb] = (f32x4){0.f,0.f,0.f,0.f};
    #pragma unroll
    for (int s=0;s<4;++s) acc[mb][s] = (f32x4){0.f,0.f,0.f,0.f};
  }

  // ---- stage tile 0 into buf 0 ----
  {
    Stage S;
    stage_load(S, xk, xv, tab, b, h, srow, sd0);
    stage_write(S, &KV[0][0][0], &KV[0][1][0], kdest, sd0, vhalf, vqd, vj);
  }
  __syncthreads();

  for (int kt=0; kt<16; ++kt){
    const int cur = kt & 1;

    // ---- issue loads for kt+1 early (latency hides under compute) ----
    Stage S;
    if (kt < 15)
      stage_load(S, xk, xv, tab, b, h, ((kt+1)<<6) + srow, sd0);

    // ---- S^T = K Q^T per kb (bias C-init = mask), exp2+pack in-register ----
    uint32_t pk[4][2][2];           // [kb][h][mb]
    __builtin_amdgcn_s_setprio(1);
    #pragma unroll
    for (int kb=0;kb<4;++kb){
      short8 kf0 = *(const short8*)&KV[cur][0][(kb<<10) + (lane<<3)];
      short8 kf1 = *(const short8*)&KV[cur][0][(kb<<10) + 512 + (lane<<3)];
      f32x4 bias = *(const f32x4*)&biasS[(kt<<6)+(kb<<4)+(quad<<2)];
      #pragma unroll
      for (int mb=0;mb<2;++mb){
        f32x4 t = mfma16(kf0, qa[mb][0], bias);
        t = mfma16(kf1, qa[mb][1], t);
        // lane holds S^T[key=kb*16+quad*4+rr][q=mb*16+l15], log2-domain
        float p0 = __builtin_amdgcn_exp2f(t.x);
        float p1 = __builtin_amdgcn_exp2f(t.y);
        float p2 = __builtin_amdgcn_exp2f(t.z);
        float p3 = __builtin_amdgcn_exp2f(t.w);
        BF2U e0; e0.h = __float22bfloat162_rn(make_float2(p0,p1));
        BF2U e1; e1.h = __float22bfloat162_rn(make_float2(p2,p3));
        pk[kb][0][mb] = e0.u;
        pk[kb][1][mb] = e1.u;
      }
    }
    __builtin_amdgcn_s_setprio(0);

    // ---- assemble P A-frags (pure register repack) ----
    short8 pa[2][2];
    #pragma unroll
    for (int mb=0;mb<2;++mb){
      U4S8 a0; a0.u = make_uint4(pk[0][0][mb], pk[1][0][mb], pk[2][0][mb], pk[3][0][mb]);
      U4S8 a1; a1.u = make_uint4(pk[0][1][mb], pk[1][1][mb], pk[2][1][mb], pk[3][1][mb]);
      pa[mb][0] = a0.s; pa[mb][1] = a1.s;
    }

    // ---- l += P * ones (matrix pipe), O += P V ----
    __builtin_amdgcn_s_setprio(1);
    #pragma unroll
    for (int mb=0;mb<2;++mb){
      l_acc[mb] = mfma16(pa[mb][0], ones, l_acc[mb]);
      l_acc[mb] = mfma16(pa[mb][1], ones, l_acc[mb]);
    }
    #pragma unroll
    for (int s=0;s<4;++s){
      short8 vb0 = *(const short8*)&KV[cur][1][(s<<10) + (lane<<3)];
      short8 vb1 = *(const short8*)&KV[cur][1][(s<<10) + 512 + (lane<<3)];
      #pragma unroll
      for (int mb=0;mb<2;++mb){
        acc[mb][s] = mfma16(pa[mb][0], vb0, acc[mb][s]);
        acc[mb][s] = mfma16(pa[mb][1], vb1, acc[mb][s]);
      }
    }
    __builtin_amdgcn_s_setprio(0);

    // ---- finish staging kt+1 into the other buffer ----
    if (kt < 15)
      stage_write(S, &KV[cur^1][0][0], &KV[cur^1][1][0], kdest, sd0, vhalf, vqd, vj);

    __syncthreads();
  }

  // ---- epilogue: l already per-q in C layout; normalize + store ----
  #pragma unroll
  for (int mb=0;mb<2;++mb){
    #pragma unroll
    for (int rr=0;rr<4;++rr){
      int qrow = qbase + (wave<<5) + (mb<<4) + (quad<<2) + rr;
      float lq = l_acc[mb][rr];
      float invl = (biasS[qrow] == 0.f && lq > 0.f) ? 1.f/lq : 0.f;
      float* ob = out + ((((size_t)b*Nn + qrow)*Hh + h)<<6);
      #pragma unroll
      for (int s=0;s<4;++s)
        ob[(s<<4)+l15] = acc[mb][s][rr]*invl;
    }
  }
}

// ============================================================
// Fallback (inline sincos, no workspace) — used if ws too small
// ============================================================
__device__ __forceinline__ void stage_rope_row_fb(const float* __restrict__ src,
                                                  u16 (*dst)[72],
                                                  int n_global, int sr, int d0)
{
  const float4* g = (const float4*)src;
  float4 a0 = g[0], a1 = g[1], a2 = g[2], a3 = g[3];
  float xx[16] = {a0.x,a0.y,a0.z,a0.w, a1.x,a1.y,a1.z,a1.w,
                  a2.x,a2.y,a2.z,a2.w, a3.x,a3.y,a3.z,a3.w};
  uint32_t w[8];
  #pragma unroll
  for (int j=0;j<8;++j){
    int i = (d0>>1)+j;
    float inv = exp2f(-(float)i * ROPE_K);
    float ang = (float)n_global * inv;
    float sn, cs; sincosf(ang, &sn, &cs);
    float x0 = xx[2*j], x1 = xx[2*j+1];
    float q0 = x0*cs - x1*sn;
    float q1 = x1*cs + x0*sn;
    w[j] = f2bf(q0) | (f2bf(q1)<<16);
  }
  *(uint4*)&dst[sr][d0]   = make_uint4(w[0],w[1],w[2],w[3]);
  *(uint4*)&dst[sr][d0+8] = make_uint4(w[4],w[5],w[6],w[7]);
}

__global__ __launch_bounds__(256,2) void attn_fallback(
    const float* __restrict__ xq, const float* __restrict__ xk,
    const float* __restrict__ xv, const int* __restrict__ vis,
    float* __restrict__ out)
{
  __shared__ u16 Qs[64][72];
  __shared__ u16 Ks[64][72];
  __shared__ u16 Vt[64][72];
  __shared__ u16 Ps[4][16][72];
  __shared__ float viss[64];

  const int tid  = threadIdx.x;
  const int wave = tid >> 6;
  const int lane = tid & 63;
  const int l15  = lane & 15;
  const int quad = lane >> 4;

  const int bid = blockIdx.x;
  const int qt = bid & 15;
  const int h  = (bid >> 4) & 7;
  const int b  = bid >> 7;

  const int sr = tid >> 2;
  const int d0 = (tid & 3) << 4;

  {
    int ng = (qt<<6) + sr;
    const float* src = xq + ((((size_t)b*Nn + ng)*Hh + h)<<6) + d0;
    stage_rope_row_fb(src, Qs, ng, sr, d0);
  }
  __syncthreads();

  short8 qa0 = *(const short8*)&Qs[(wave<<4)+l15][quad<<3];
  short8 qa1 = *(const short8*)&Qs[(wave<<4)+l15][(quad<<3)+32];

  f32x4 acc[4];
  #pragma unroll
  for (int s=0;s<4;++s) acc[s] = (f32x4){0.f,0.f,0.f,0.f};
  float m_r[4], l_r[4];
  #pragma unroll
  for (int rr=0;rr<4;++rr){ m_r[rr] = -1e30f; l_r[rr] = 0.f; }

  for (int kt=0; kt<16; ++kt){
    __syncthreads();
    {
      int ng = (kt<<6) + sr;
      const float* src = xk + ((((size_t)b*Nn + ng)*Hh + h)<<6) + d0;
      stage_rope_row_fb(src, Ks, ng, sr, d0);
    }
    {
      int ng = (kt<<6) + sr;
      const float4* g = (const float4*)(xv + ((((size_t)b*Nn + ng)*Hh + h)<<6) + d0);
      float4 a0 = g[0], a1 = g[1], a2 = g[2], a3 = g[3];
      float vv16[16] = {a0.x,a0.y,a0.z,a0.w, a1.x,a1.y,a1.z,a1.w,
                        a2.x,a2.y,a2.z,a2.w, a3.x,a3.y,a3.z,a3.w};
      #pragma unroll
      for (int j=0;j<16;++j) Vt[d0+j][sr] = (u16)f2bf(vv16[j]);
    }
    if (tid < 64) viss[tid] = (vis[b*Nn + (kt<<6) + tid] != 0) ? 1.f : 0.f;
    __syncthreads();

    f32x4 s4[4];
    #pragma unroll
    for (int n=0;n<4;++n){
      short8 kb0 = *(const short8*)&Ks[(n<<4)+l15][quad<<3];
      short8 kb1 = *(const short8*)&Ks[(n<<4)+l15][(quad<<3)+32];
      f32x4 t = (f32x4){0.f,0.f,0.f,0.f};
      t = mfma16(qa0, kb0, t);
      t = mfma16(qa1, kb1, t);
      s4[n] = t;
    }
    float vv[4];
    #pragma unroll
    for (int n=0;n<4;++n) vv[n] = viss[(n<<4)+l15];

    float p[4][4];
    #pragma unroll
    for (int rr=0; rr<4; ++rr){
      float sc[4];
      #pragma unroll
      for (int n=0;n<4;++n) sc[n] = (vv[n] > 0.f) ? s4[n][rr]*0.125f : -1e30f;
      float tm = fmaxf(fmaxf(sc[0],sc[1]), fmaxf(sc[2],sc[3]));
      tm = fmaxf(tm, __shfl_xor(tm,1));
      tm = fmaxf(tm, __shfl_xor(tm,2));
      tm = fmaxf(tm, __shfl_xor(tm,4));
      tm = fmaxf(tm, __shfl_xor(tm,8));
      float mnew  = fmaxf(m_r[rr], tm);
      float alpha = __expf(m_r[rr] - mnew);
      m_r[rr] = mnew;
      float psum = 0.f;
      #pragma unroll
      for (int n=0;n<4;++n){
        float pv = (vv[n] > 0.f) ? __expf(sc[n] - mnew) : 0.f;
        p[n][rr] = pv; psum += pv;
      }
      l_r[rr] = l_r[rr]*alpha + psum;
      #pragma unroll
      for (int s=0;s<4;++s) acc[s][rr] *= alpha;
    }

    #pragma unroll
    for (int n=0;n<4;++n)
      #pragma unroll
      for (int rr=0;rr<4;++rr)
        Ps[wave][(quad<<2)+rr][(n<<4)+l15] = (u16)f2bf(p[n][rr]);
    asm volatile("s_waitcnt lgkmcnt(0)" ::: "memory");
    short8 pa0 = *(const short8*)&Ps[wave][l15][quad<<3];
    short8 pa1 = *(const short8*)&Ps[wave][l15][(quad<<3)+32];

    #pragma unroll
    for (int s=0;s<4;++s){
      short8 vb0 = *(const short8*)&Vt[(s<<4)+l15][quad<<3];
      short8 vb1 = *(const short8*)&Vt[(s<<4)+l15][(quad<<3)+32];
      acc[s] = mfma16(pa0, vb0, acc[s]);
      acc[s] = mfma16(pa1, vb1, acc[s]);
    }
  }

  #pragma unroll
  for (int rr=0;rr<4;++rr){
    float t = l_r[rr];
    t += __shfl_xor(t,1); t += __shfl_xor(t,2);
    t += __shfl_xor(t,4); t += __shfl_xor(t,8);
    int row = (qt<<6) + (wave<<4) + (quad<<2) + rr;
    int qv  = vis[b*Nn + row];
    float invl = (qv != 0 && t > 0.f) ? 1.f/t : 0.f;
    size_t obase = (((size_t)b*Nn + row)*Hh + h) << 6;
    #pragma unroll
    for (int s=0;s<4;++s)
      out[obase + (s<<4) + l15] = acc[s][rr]*invl;
  }
}

extern "C" void kernel_launch(void* const* d_in, const int* in_sizes, int n_in,
                              void* d_out, int out_size, void* d_ws, size_t ws_size,
                              hipStream_t stream)
{
  const float* xq = (const float*)d_in[0];
  const float* xk = (const float*)d_in[1];
  const float* xv = (const float*)d_in[2];
  const int* vis  = (const int*)d_in[3];
  float* out = (float*)d_out;

  const size_t tab_bytes = (size_t)32*1024*sizeof(float2);   // 256 KB

  if (d_ws != nullptr && ws_size >= tab_bytes){
    float2* tab = (float2*)d_ws;
    rope_table_kernel<<<dim3(128), dim3(256), 0, stream>>>(tab);
    fused_attn_kernel<<<dim3(Bb*Hh*4), dim3(512), 0, stream>>>(xq, xk, xv, vis, tab, out);
  } else {
    attn_fallback<<<dim3(Bb*Hh*(Nn/64)), dim3(256), 0, stream>>>(xq, xk, xv, vis, out);
  }
}

// Round 6
// 176.859 us; speedup vs baseline: 1.0278x; 1.0278x over previous
//
#include <hip/hip_runtime.h>
#include <hip/hip_bf16.h>
#include <stdint.h>

#define Bb 16
#define Nn 1024
#define Hh 8
#define Dd 64

typedef unsigned short u16;
typedef float f32x4 __attribute__((ext_vector_type(4)));
typedef short short8 __attribute__((ext_vector_type(8)));

union U4S8 { uint4 u; short8 s; };
union BF2U { __hip_bfloat162 h; uint32_t u; };

__device__ __forceinline__ uint32_t f2bf(float f){
  union{float f;uint32_t i;} v; v.f=f;
  return (v.i + 0x7fffu + ((v.i>>16)&1u))>>16;
}

__device__ __forceinline__ f32x4 mfma16(short8 a, short8 b, f32x4 c){
  return __builtin_amdgcn_mfma_f32_16x16x32_bf16(a,b,c,0,0,0);
}

// log2(10000)/32
#define ROPE_K 0.41524101186092030f
// 0.125 * log2(e)  (sm_scale folded with exp->exp2 conversion)
#define QS 0.18033688011112042f
#define NEGBIG -1.0e30f

// ============================================================
// cos/sin table, layout [n][i]: tab[(n<<5)+i] = {cos(n*invfreq_i),
// sin(n*invfreq_i)}, n in [0,1024), i in [0,32).  256 KB, 32K sincos.
// ============================================================
__global__ __launch_bounds__(256) void rope_table_kernel(float2* __restrict__ tab)
{
  int id = blockIdx.x*256 + threadIdx.x;   // 32768 total
  int n = id >> 5, i = id & 31;
  float inv = exp2f(-(float)i * ROPE_K);
  float sn, cs; sincosf((float)n * inv, &sn, &cs);
  tab[id] = make_float2(cs, sn);
}

// ============================================================
// Fused staging, R6 conflict-free version.
// R5's V staging wrote 8 scalar u16/thread whose bank index depended
// only on jj (+2 vj values) -> ~32-way conflict, SQ_LDS_BANK_CONFLICT
// = 1.94e7 = 76K cyc/CU = 31.6us -- exactly the 87-56us regression.
// Fix: invert the slot permutation in the THREAD MAPPING instead of
// the address.  slot(k)= k0 | k4<<1 | k5<<2 | k2<<3 | k3<<4 | k1<<5,
// so for fixed (vhalf=g&1, vqd=(g>>1)&3) the 8 slot-consecutive keys
// are {16m + 2g + p}.  Thread (g=tid>>6, d=tid&63) loads those 8 rows
// at column d (8 dword loads, lane=d => wave-coalesced 256B each),
// packs in register order, and writes ONE uint4 at elem
//   (d>>4)<<10 | (g&1)<<9 | ((g>>1)&3)<<7 | (d&15)<<3
// -> start bank 4*(d&7): uniform minimal distribution, same pattern
// as the fragment reads that measured 0 conflicts.  LDS layout is
// bit-identical to the verified R4/R5 fragment-linear layout:
//   K elem = kb*1024 + half*512 + quad*128 + l15*8 + j
//   V elem = s*1024  + half*512 + qd*128  + l15v*8 + j
// ============================================================
struct Stage {
  float4 ka0, ka1, c0, c1;
  float v[8];
};

__device__ __forceinline__ void stage_load(Stage& S,
    const float* __restrict__ xk, const float* __restrict__ xv,
    const float2* __restrict__ tab, int b, int h, int n, int sd0,
    int vrow0, int vlane)
{
  const float4* kg = (const float4*)(xk + ((((size_t)b*Nn + n)*Hh + h)<<6) + sd0);
  S.ka0 = kg[0]; S.ka1 = kg[1];
  const float4* tg = (const float4*)(tab + (n<<5) + (sd0>>1));  // 32B aligned
  S.c0 = tg[0]; S.c1 = tg[1];
  // V rows vrow0 + {0,1} + 16m, column vlane (each load wave-coalesced)
  const float* vb = xv + ((((size_t)b*Nn + vrow0)*Hh + h)<<6) + vlane;
  #pragma unroll
  for (int m=0;m<4;++m){
    S.v[2*m]   = vb[(16*m)*Hh*Dd];
    S.v[2*m+1] = vb[(16*m+1)*Hh*Dd];
  }
}

__device__ __forceinline__ void stage_write(const Stage& S,
    u16* __restrict__ Kl, u16* __restrict__ Vl, int kdest, int vdest)
{
  float kx[8]  = {S.ka0.x,S.ka0.y,S.ka0.z,S.ka0.w, S.ka1.x,S.ka1.y,S.ka1.z,S.ka1.w};
  float cs4[4] = {S.c0.x, S.c0.z, S.c1.x, S.c1.z};
  float sn4[4] = {S.c0.y, S.c0.w, S.c1.y, S.c1.w};
  uint32_t w[4];
  #pragma unroll
  for (int j=0;j<4;++j){
    float x0 = kx[2*j], x1 = kx[2*j+1];
    float q0 = x0*cs4[j] - x1*sn4[j];
    float q1 = x1*cs4[j] + x0*sn4[j];
    w[j] = f2bf(q0) | (f2bf(q1)<<16);
  }
  *(uint4*)&Kl[kdest] = make_uint4(w[0],w[1],w[2],w[3]);
  uint32_t wv[4];
  #pragma unroll
  for (int j=0;j<4;++j)
    wv[j] = f2bf(S.v[2*j]) | (f2bf(S.v[2*j+1])<<16);
  *(uint4*)&Vl[vdest] = make_uint4(wv[0],wv[1],wv[2],wv[3]);
}

// ============================================================
// Fused attention.  Grid 512 x 512thr (8 waves), 2 blocks/CU, 256 q
// rows per block (per-wave compute identical to verified R4: mb=2).
// Each block ropes K / permutes V from raw f32 into LDS itself; the
// 4 blocks per (b,h) share an XCD so redundant f32 reads are L2 hits.
// T14 split staging: loads at top of iter kt, writes after PV.
// ============================================================
__global__ __launch_bounds__(512,4) void fused_attn_kernel(
    const float* __restrict__ xq, const float* __restrict__ xk,
    const float* __restrict__ xv, const int* __restrict__ vis,
    const float2* __restrict__ tab, float* __restrict__ out)
{
  __shared__ u16 KV[2][2][4096];    // [buf][K/V][frag-linear], 32 KiB
  __shared__ float biasS[Nn];       // key-bias 0 / -1e30, 4 KiB

  const int tid  = threadIdx.x;     // 0..511
  const int lane = tid & 63;
  const int wave = tid >> 6;        // 0..7
  const int l15  = lane & 15;
  const int quad = lane >> 4;

  // ---- XCD-aware decode (grid 512, 8 XCDs, 64 blocks/XCD) ----
  const int bid = blockIdx.x;
  const int xcd = bid & 7;
  const int ix  = bid >> 3;            // 0..63
  const int bh_ = (xcd<<4) | (ix>>2);  // 16 bh per XCD, 4 qt adjacent
  const int qt  = ix & 3;
  const int h   = bh_ & 7;
  const int b   = bh_ >> 3;
  const int qbase = qt<<8;             // 256 q rows per block

  const int* visb = vis + b*Nn;

  // ---- staging thread mappings ----
  // K: 64 rows x 8 d-blocks
  const int srow = tid >> 3;           // key row in tile
  const int sd0  = (tid & 7) << 3;     // 8-d block
  const int kdest = ((srow>>4)<<10) + ((sd0>>5)<<9) + (((sd0>>3)&3)<<7) + ((srow&15)<<3);
  // V: 8 slot-groups x 64 d-columns (conflict-free uint4 dest)
  const int vgrp  = tid >> 6;          // 0..7
  const int vlane = tid & 63;          // d column
  const int vdest = ((vlane>>4)<<10) + ((vgrp&1)<<9) + (((vgrp>>1)&3)<<7) + ((vlane&15)<<3);

  // ---- stage vis -> f32 bias in LDS (once) ----
  {
    int2 vi = *(const int2*)&visb[tid<<1];
    float2 bs;
    bs.x = vi.x ? 0.f : NEGBIG;
    bs.y = vi.y ? 0.f : NEGBIG;
    *(float2*)&biasS[tid<<1] = bs;
  }

  // ---- roped Q B-frags in registers (QS folded), 2 m-blocks ----
  short8 qa[2][2];
  #pragma unroll
  for (int mb=0; mb<2; ++mb){
    int n = qbase + (wave<<5) + (mb<<4) + l15;
    const float* src = xq + ((((size_t)b*Nn + n)*Hh + h)<<6);
    #pragma unroll
    for (int half=0; half<2; ++half){
      int d0 = (half<<5) + (quad<<3);
      const float4* g = (const float4*)(src + d0);
      float4 u0 = g[0], u1 = g[1];
      float xx[8] = {u0.x,u0.y,u0.z,u0.w, u1.x,u1.y,u1.z,u1.w};
      uint32_t w[4];
      #pragma unroll
      for (int j=0;j<4;++j){
        int i2 = (d0>>1) + j;
        float2 t = tab[(n<<5)+i2];
        float x0 = xx[2*j], x1 = xx[2*j+1];
        float q0 = (x0*t.x - x1*t.y)*QS;
        float q1 = (x1*t.x + x0*t.y)*QS;
        w[j] = f2bf(q0) | (f2bf(q1)<<16);
      }
      U4S8 t2; t2.u = make_uint4(w[0],w[1],w[2],w[3]);
      qa[mb][half] = t2.s;
    }
  }

  U4S8 ones_u; ones_u.u = make_uint4(0x3F803F80u,0x3F803F80u,0x3F803F80u,0x3F803F80u);
  const short8 ones = ones_u.s;

  f32x4 acc[2][4];
  f32x4 l_acc[2];
  #pragma unroll
  for (int mb=0;mb<2;++mb){
    l_acc[mb] = (f32x4){0.f,0.f,0.f,0.f};
    #pragma unroll
    for (int s=0;s<4;++s) acc[mb][s] = (f32x4){0.f,0.f,0.f,0.f};
  }

  // ---- stage tile 0 into buf 0 ----
  {
    Stage S;
    stage_load(S, xk, xv, tab, b, h, srow, sd0, vgrp<<1, vlane);
    stage_write(S, &KV[0][0][0], &KV[0][1][0], kdest, vdest);
  }
  __syncthreads();

  for (int kt=0; kt<16; ++kt){
    const int cur = kt & 1;

    // ---- issue loads for kt+1 early (latency hides under compute) ----
    Stage S;
    if (kt < 15)
      stage_load(S, xk, xv, tab, b, h, ((kt+1)<<6) + srow, sd0,
                 ((kt+1)<<6) + (vgrp<<1), vlane);

    // ---- S^T = K Q^T per kb (bias C-init = mask), exp2+pack in-register ----
    uint32_t pk[4][2][2];           // [kb][h][mb]
    __builtin_amdgcn_s_setprio(1);
    #pragma unroll
    for (int kb=0;kb<4;++kb){
      short8 kf0 = *(const short8*)&KV[cur][0][(kb<<10) + (lane<<3)];
      short8 kf1 = *(const short8*)&KV[cur][0][(kb<<10) + 512 + (lane<<3)];
      f32x4 bias = *(const f32x4*)&biasS[(kt<<6)+(kb<<4)+(quad<<2)];
      #pragma unroll
      for (int mb=0;mb<2;++mb){
        f32x4 t = mfma16(kf0, qa[mb][0], bias);
        t = mfma16(kf1, qa[mb][1], t);
        // lane holds S^T[key=kb*16+quad*4+rr][q=mb*16+l15], log2-domain
        float p0 = __builtin_amdgcn_exp2f(t.x);
        float p1 = __builtin_amdgcn_exp2f(t.y);
        float p2 = __builtin_amdgcn_exp2f(t.z);
        float p3 = __builtin_amdgcn_exp2f(t.w);
        BF2U e0; e0.h = __float22bfloat162_rn(make_float2(p0,p1));
        BF2U e1; e1.h = __float22bfloat162_rn(make_float2(p2,p3));
        pk[kb][0][mb] = e0.u;
        pk[kb][1][mb] = e1.u;
      }
    }
    __builtin_amdgcn_s_setprio(0);

    // ---- assemble P A-frags (pure register repack) ----
    short8 pa[2][2];
    #pragma unroll
    for (int mb=0;mb<2;++mb){
      U4S8 a0; a0.u = make_uint4(pk[0][0][mb], pk[1][0][mb], pk[2][0][mb], pk[3][0][mb]);
      U4S8 a1; a1.u = make_uint4(pk[0][1][mb], pk[1][1][mb], pk[2][1][mb], pk[3][1][mb]);
      pa[mb][0] = a0.s; pa[mb][1] = a1.s;
    }

    // ---- l += P * ones (matrix pipe), O += P V ----
    __builtin_amdgcn_s_setprio(1);
    #pragma unroll
    for (int mb=0;mb<2;++mb){
      l_acc[mb] = mfma16(pa[mb][0], ones, l_acc[mb]);
      l_acc[mb] = mfma16(pa[mb][1], ones, l_acc[mb]);
    }
    #pragma unroll
    for (int s=0;s<4;++s){
      short8 vb0 = *(const short8*)&KV[cur][1][(s<<10) + (lane<<3)];
      short8 vb1 = *(const short8*)&KV[cur][1][(s<<10) + 512 + (lane<<3)];
      #pragma unroll
      for (int mb=0;mb<2;++mb){
        acc[mb][s] = mfma16(pa[mb][0], vb0, acc[mb][s]);
        acc[mb][s] = mfma16(pa[mb][1], vb1, acc[mb][s]);
      }
    }
    __builtin_amdgcn_s_setprio(0);

    // ---- finish staging kt+1 into the other buffer ----
    if (kt < 15)
      stage_write(S, &KV[cur^1][0][0], &KV[cur^1][1][0], kdest, vdest);

    __syncthreads();
  }

  // ---- epilogue: l already per-q in C layout; normalize + store ----
  #pragma unroll
  for (int mb=0;mb<2;++mb){
    #pragma unroll
    for (int rr=0;rr<4;++rr){
      int qrow = qbase + (wave<<5) + (mb<<4) + (quad<<2) + rr;
      float lq = l_acc[mb][rr];
      float invl = (biasS[qrow] == 0.f && lq > 0.f) ? 1.f/lq : 0.f;
      float* ob = out + ((((size_t)b*Nn + qrow)*Hh + h)<<6);
      #pragma unroll
      for (int s=0;s<4;++s)
        ob[(s<<4)+l15] = acc[mb][s][rr]*invl;
    }
  }
}

// ============================================================
// Fallback (inline sincos, no workspace) — used if ws too small
// ============================================================
__device__ __forceinline__ void stage_rope_row_fb(const float* __restrict__ src,
                                                  u16 (*dst)[72],
                                                  int n_global, int sr, int d0)
{
  const float4* g = (const float4*)src;
  float4 a0 = g[0], a1 = g[1], a2 = g[2], a3 = g[3];
  float xx[16] = {a0.x,a0.y,a0.z,a0.w, a1.x,a1.y,a1.z,a1.w,
                  a2.x,a2.y,a2.z,a2.w, a3.x,a3.y,a3.z,a3.w};
  uint32_t w[8];
  #pragma unroll
  for (int j=0;j<8;++j){
    int i = (d0>>1)+j;
    float inv = exp2f(-(float)i * ROPE_K);
    float ang = (float)n_global * inv;
    float sn, cs; sincosf(ang, &sn, &cs);
    float x0 = xx[2*j], x1 = xx[2*j+1];
    float q0 = x0*cs - x1*sn;
    float q1 = x1*cs + x0*sn;
    w[j] = f2bf(q0) | (f2bf(q1)<<16);
  }
  *(uint4*)&dst[sr][d0]   = make_uint4(w[0],w[1],w[2],w[3]);
  *(uint4*)&dst[sr][d0+8] = make_uint4(w[4],w[5],w[6],w[7]);
}

__global__ __launch_bounds__(256,2) void attn_fallback(
    const float* __restrict__ xq, const float* __restrict__ xk,
    const float* __restrict__ xv, const int* __restrict__ vis,
    float* __restrict__ out)
{
  __shared__ u16 Qs[64][72];
  __shared__ u16 Ks[64][72];
  __shared__ u16 Vt[64][72];
  __shared__ u16 Ps[4][16][72];
  __shared__ float viss[64];

  const int tid  = threadIdx.x;
  const int wave = tid >> 6;
  const int lane = tid & 63;
  const int l15  = lane & 15;
  const int quad = lane >> 4;

  const int bid = blockIdx.x;
  const int qt = bid & 15;
  const int h  = (bid >> 4) & 7;
  const int b  = bid >> 7;

  const int sr = tid >> 2;
  const int d0 = (tid & 3) << 4;

  {
    int ng = (qt<<6) + sr;
    const float* src = xq + ((((size_t)b*Nn + ng)*Hh + h)<<6) + d0;
    stage_rope_row_fb(src, Qs, ng, sr, d0);
  }
  __syncthreads();

  short8 qa0 = *(const short8*)&Qs[(wave<<4)+l15][quad<<3];
  short8 qa1 = *(const short8*)&Qs[(wave<<4)+l15][(quad<<3)+32];

  f32x4 acc[4];
  #pragma unroll
  for (int s=0;s<4;++s) acc[s] = (f32x4){0.f,0.f,0.f,0.f};
  float m_r[4], l_r[4];
  #pragma unroll
  for (int rr=0;rr<4;++rr){ m_r[rr] = -1e30f; l_r[rr] = 0.f; }

  for (int kt=0; kt<16; ++kt){
    __syncthreads();
    {
      int ng = (kt<<6) + sr;
      const float* src = xk + ((((size_t)b*Nn + ng)*Hh + h)<<6) + d0;
      stage_rope_row_fb(src, Ks, ng, sr, d0);
    }
    {
      int ng = (kt<<6) + sr;
      const float4* g = (const float4*)(xv + ((((size_t)b*Nn + ng)*Hh + h)<<6) + d0);
      float4 a0 = g[0], a1 = g[1], a2 = g[2], a3 = g[3];
      float vv16[16] = {a0.x,a0.y,a0.z,a0.w, a1.x,a1.y,a1.z,a1.w,
                        a2.x,a2.y,a2.z,a2.w, a3.x,a3.y,a3.z,a3.w};
      #pragma unroll
      for (int j=0;j<16;++j) Vt[d0+j][sr] = (u16)f2bf(vv16[j]);
    }
    if (tid < 64) viss[tid] = (vis[b*Nn + (kt<<6) + tid] != 0) ? 1.f : 0.f;
    __syncthreads();

    f32x4 s4[4];
    #pragma unroll
    for (int n=0;n<4;++n){
      short8 kb0 = *(const short8*)&Ks[(n<<4)+l15][quad<<3];
      short8 kb1 = *(const short8*)&Ks[(n<<4)+l15][(quad<<3)+32];
      f32x4 t = (f32x4){0.f,0.f,0.f,0.f};
      t = mfma16(qa0, kb0, t);
      t = mfma16(qa1, kb1, t);
      s4[n] = t;
    }
    float vv[4];
    #pragma unroll
    for (int n=0;n<4;++n) vv[n] = viss[(n<<4)+l15];

    float p[4][4];
    #pragma unroll
    for (int rr=0; rr<4; ++rr){
      float sc[4];
      #pragma unroll
      for (int n=0;n<4;++n) sc[n] = (vv[n] > 0.f) ? s4[n][rr]*0.125f : -1e30f;
      float tm = fmaxf(fmaxf(sc[0],sc[1]), fmaxf(sc[2],sc[3]));
      tm = fmaxf(tm, __shfl_xor(tm,1));
      tm = fmaxf(tm, __shfl_xor(tm,2));
      tm = fmaxf(tm, __shfl_xor(tm,4));
      tm = fmaxf(tm, __shfl_xor(tm,8));
      float mnew  = fmaxf(m_r[rr], tm);
      float alpha = __expf(m_r[rr] - mnew);
      m_r[rr] = mnew;
      float psum = 0.f;
      #pragma unroll
      for (int n=0;n<4;++n){
        float pv = (vv[n] > 0.f) ? __expf(sc[n] - mnew) : 0.f;
        p[n][rr] = pv; psum += pv;
      }
      l_r[rr] = l_r[rr]*alpha + psum;
      #pragma unroll
      for (int s=0;s<4;++s) acc[s][rr] *= alpha;
    }

    #pragma unroll
    for (int n=0;n<4;++n)
      #pragma unroll
      for (int rr=0;rr<4;++rr)
        Ps[wave][(quad<<2)+rr][(n<<4)+l15] = (u16)f2bf(p[n][rr]);
    asm volatile("s_waitcnt lgkmcnt(0)" ::: "memory");
    short8 pa0 = *(const short8*)&Ps[wave][l15][quad<<3];
    short8 pa1 = *(const short8*)&Ps[wave][l15][(quad<<3)+32];

    #pragma unroll
    for (int s=0;s<4;++s){
      short8 vb0 = *(const short8*)&Vt[(s<<4)+l15][quad<<3];
      short8 vb1 = *(const short8*)&Vt[(s<<4)+l15][(quad<<3)+32];
      acc[s] = mfma16(pa0, vb0, acc[s]);
      acc[s] = mfma16(pa1, vb1, acc[s]);
    }
  }

  #pragma unroll
  for (int rr=0;rr<4;++rr){
    float t = l_r[rr];
    t += __shfl_xor(t,1); t += __shfl_xor(t,2);
    t += __shfl_xor(t,4); t += __shfl_xor(t,8);
    int row = (qt<<6) + (wave<<4) + (quad<<2) + rr;
    int qv  = vis[b*Nn + row];
    float invl = (qv != 0 && t > 0.f) ? 1.f/t : 0.f;
    size_t obase = (((size_t)b*Nn + row)*Hh + h) << 6;
    #pragma unroll
    for (int s=0;s<4;++s)
      out[obase + (s<<4) + l15] = acc[s][rr]*invl;
  }
}

extern "C" void kernel_launch(void* const* d_in, const int* in_sizes, int n_in,
                              void* d_out, int out_size, void* d_ws, size_t ws_size,
                              hipStream_t stream)
{
  const float* xq = (const float*)d_in[0];
  const float* xk = (const float*)d_in[1];
  const float* xv = (const float*)d_in[2];
  const int* vis  = (const int*)d_in[3];
  float* out = (float*)d_out;

  const size_t tab_bytes = (size_t)32*1024*sizeof(float2);   // 256 KB

  if (d_ws != nullptr && ws_size >= tab_bytes){
    float2* tab = (float2*)d_ws;
    rope_table_kernel<<<dim3(128), dim3(256), 0, stream>>>(tab);
    fused_attn_kernel<<<dim3(Bb*Hh*4), dim3(512), 0, stream>>>(xq, xk, xv, vis, tab, out);
  } else {
    attn_fallback<<<dim3(Bb*Hh*(Nn/64)), dim3(256), 0, stream>>>(xq, xk, xv, vis, out);
  }
}